// Round 13
// baseline (612.265 us; speedup 1.0000x reference)
//
#include <hip/hip_runtime.h>
#include <hip/hip_bf16.h>

typedef __attribute__((ext_vector_type(8))) short bf16x8;
typedef __attribute__((ext_vector_type(4))) float f32x4;
typedef __attribute__((ext_vector_type(4))) unsigned short u16x4;

#define BB 4
#define SS 2048
#define DD 2048
#define HH 16
#define HDD 128
// QK buffer: [B*S][4096] bf16 (Q cols 0..2047, K cols 2048..4095), RoPE pre-applied
// Vt buffer: [B*H][128][2048] bf16 (V transposed: hd-major, s contiguous)
// Masking sentinels: finite so (masked) - (init) never yields exp2(0)=1.
#define MASKV (-30000.0f)
#define MINIT (-15000.0f)

__device__ __forceinline__ unsigned short f2bf(float f) {
  __hip_bfloat16 b = __float2bfloat16(f);
  return *reinterpret_cast<unsigned short*>(&b);
}
__device__ __forceinline__ void gl_lds16(const void* g, void* l) {
  __builtin_amdgcn_global_load_lds((const __attribute__((address_space(1))) unsigned int*)g,
                                   (__attribute__((address_space(3))) unsigned int*)l, 16, 0, 0);
}

// ---------------- fp32 -> bf16 conversion (vectorized) ----------------
__global__ __launch_bounds__(256) void convertk(const float* __restrict__ src,
                                                __hip_bfloat16* __restrict__ dst, int n4) {
  int i = blockIdx.x * 256 + threadIdx.x;
  if (i >= n4) return;
  f32x4 v = ((const f32x4*)src)[i];
  u16x4 o;
  o[0] = f2bf(v[0]); o[1] = f2bf(v[1]); o[2] = f2bf(v[2]); o[3] = f2bf(v[3]);
  ((u16x4*)dst)[i] = o;
}

// ---------------- 256x256 8-wave B^T GEMM, ring-of-4 + 2-phase interleave ------
// C[m][n] = sum_k A[m][k] * Bw[n][k].  BK=32, FOUR ring LDS buffers (4x32KB=128KB).
// Per K-tile T (buf T&3), two phases with fine ds_read | stage | MFMA interleave
// (m196: the per-phase interleave is the lever; m218b: setprio pays only with it):
//   top:  vmcnt(4*min(2,NT-1-T))   // drains stage(T); stage(T+1),(T+2) in flight
//         s_barrier
//   P1:   stage A(T+3) (2 gl_lds) | read bg[0..3]+af[0..3] (8 ds_read_b128)
//         | setprio1 | 16 MFMA (mi0-3) | setprio0 | s_barrier
//   P2:   stage B(T+3) (2 gl_lds) | read af[4..7] (4)
//         | setprio1 | 16 MFMA (mi4-7) | setprio0
// Issue-order simulation (steady): at T.top outstanding = stage(T+1)+stage(T+2)
// = 8 loads -> vmcnt(8) drains exactly stage(T). Ring distance 3 for the writer:
// buf[(T+3)&3] disjoint from read buf[T&3] and from T+1/T+2's buffers.
// Swizzle: chunk j ^= (row>>1)&3 (verified 0 bank conflicts, rounds 12 PMC).
// MODE 0: epilogue -> QK buffer with fused RoPE (n<4096) or Vt (transposed).
// MODE 1: epilogue -> float C row-major [M][N].
template <int MODE>
__global__ __launch_bounds__(512, 1) void gemm256(const __hip_bfloat16* __restrict__ A,
                                                  const __hip_bfloat16* __restrict__ Bw,
                                                  __hip_bfloat16* __restrict__ Cbf,
                                                  __hip_bfloat16* __restrict__ Vt,
                                                  float* __restrict__ Cf,
                                                  const float* __restrict__ fc,
                                                  const float* __restrict__ fs,
                                                  const int* __restrict__ posp,
                                                  int M, int N, int K) {
  __shared__ __hip_bfloat16 As[4][256 * 32];  // ring buffers, 16KB each
  __shared__ __hip_bfloat16 Bs[4][256 * 32];
  const int tid = threadIdx.x;
  const int wid = tid >> 6, lane = tid & 63;
  const int l15 = lane & 15, l4 = lane >> 4;
  const int wm = wid >> 2, wn = wid & 3;  // 2 x 4 wave grid; wave owns 128x64

  const int nbn = N >> 8;
  const int nb = (M >> 8) * nbn;
  const int bid = blockIdx.x;
  const int swz = (bid & 7) * (nb >> 3) + (bid >> 3);  // XCD-contiguous (nb%8==0)
  const int bm = swz / nbn, bn = swz % nbn;

  const int NT = K >> 5;  // K-tiles of 32

#define STAGE_A(TT, BUF)                                                          \
  {                                                                               \
    const int k0_ = (TT) << 5;                                                    \
    _Pragma("unroll") for (int i = 0; i < 2; i++) {                               \
      int c = i * 512 + tid, rr = c >> 2, jj = (c & 3) ^ ((rr >> 1) & 3);         \
      gl_lds16(A + ((long)bm * 256 + rr) * K + k0_ + jj * 8, &As[BUF][0] + c * 8);\
    }                                                                             \
  }
#define STAGE_B(TT, BUF)                                                          \
  {                                                                               \
    const int k0_ = (TT) << 5;                                                    \
    _Pragma("unroll") for (int i = 0; i < 2; i++) {                               \
      int c = i * 512 + tid, rr = c >> 2, jj = (c & 3) ^ ((rr >> 1) & 3);         \
      gl_lds16(Bw + ((long)bn * 256 + rr) * K + k0_ + jj * 8, &Bs[BUF][0] + c * 8);\
    }                                                                             \
  }

  f32x4 acc[8][4] = {};

  // prologue: tiles 0,1,2 staged (12 loads in flight; counted waits cover them)
  STAGE_A(0, 0); STAGE_B(0, 0);
  STAGE_A(1, 1); STAGE_B(1, 1);
  STAGE_A(2, 2); STAGE_B(2, 2);

  for (int T = 0; T < NT; ++T) {
    const int cb = T & 3;
    const int rem = NT - 1 - T;

    // tile-top counted drain: stage(T) visible; stage(T+1),(T+2) stay in flight
    if (rem >= 2)      asm volatile("s_waitcnt vmcnt(8)" ::: "memory");
    else if (rem == 1) asm volatile("s_waitcnt vmcnt(4)" ::: "memory");
    else               asm volatile("s_waitcnt vmcnt(0)" ::: "memory");
    __builtin_amdgcn_s_barrier();
    asm volatile("" ::: "memory");

    // ---- phase 1: stage A(T+3) | read bg[0..3]+af[0..3] | 16 MFMA (mi 0-3) ----
    if (T + 3 < NT) STAGE_A(T + 3, (T + 3) & 3);
    bf16x8 bg[4], af0[4];
#pragma unroll
    for (int ni = 0; ni < 4; ni++) {
      int r = wn * 64 + ni * 16 + l15;
      int j = l4 ^ ((r >> 1) & 3);
      bg[ni] = *(const bf16x8*)(&Bs[cb][0] + r * 32 + j * 8);
    }
#pragma unroll
    for (int mi = 0; mi < 4; mi++) {
      int r = wm * 128 + mi * 16 + l15;
      int j = l4 ^ ((r >> 1) & 3);
      af0[mi] = *(const bf16x8*)(&As[cb][0] + r * 32 + j * 8);
    }
    __builtin_amdgcn_s_setprio(1);
#pragma unroll
    for (int mi = 0; mi < 4; mi++)
#pragma unroll
      for (int ni = 0; ni < 4; ni++)
        acc[mi][ni] = __builtin_amdgcn_mfma_f32_16x16x32_bf16(af0[mi], bg[ni],
                                                              acc[mi][ni], 0, 0, 0);
    __builtin_amdgcn_s_setprio(0);
    __builtin_amdgcn_s_barrier();
    asm volatile("" ::: "memory");

    // ---- phase 2: stage B(T+3) | read af[4..7] | 16 MFMA (mi 4-7) ----
    if (T + 3 < NT) STAGE_B(T + 3, (T + 3) & 3);
    bf16x8 af1[4];
#pragma unroll
    for (int mi = 0; mi < 4; mi++) {
      int r = wm * 128 + (mi + 4) * 16 + l15;
      int j = l4 ^ ((r >> 1) & 3);
      af1[mi] = *(const bf16x8*)(&As[cb][0] + r * 32 + j * 8);
    }
    __builtin_amdgcn_s_setprio(1);
#pragma unroll
    for (int mi = 0; mi < 4; mi++)
#pragma unroll
      for (int ni = 0; ni < 4; ni++)
        acc[mi + 4][ni] = __builtin_amdgcn_mfma_f32_16x16x32_bf16(af1[mi], bg[ni],
                                                                  acc[mi + 4][ni], 0, 0, 0);
    __builtin_amdgcn_s_setprio(0);
    // no trailing barrier: next tile's top vmcnt+barrier orders buf reuse
  }
#undef STAGE_A
#undef STAGE_B

  // ---- epilogue ----
  if (MODE == 0) {
    if (bn * 256 < 4096) {
      const int pos = *posp;
#pragma unroll
      for (int mi = 0; mi < 8; mi++)
#pragma unroll
        for (int ni = 0; ni < 4; ni++) {
          int n = bn * 256 + wn * 64 + ni * 16 + l15;
          int hd = n & 127;
          int ip = hd >> 1;
          bool odd = hd & 1;
#pragma unroll
          for (int r = 0; r < 4; r++) {
            float v = acc[mi][ni][r];
            float p = __shfl_xor(v, 1, 64);
            int m = bm * 256 + wm * 128 + mi * 16 + l4 * 4 + r;
            int s = m & (SS - 1);
            float cv = fc[(long)(pos + s) * 64 + ip];
            float sv = fs[(long)(pos + s) * 64 + ip];
            float out = odd ? (p * sv + v * cv) : (v * cv - p * sv);
            Cbf[(long)m * 4096 + n] = __float2bfloat16(out);
          }
        }
    } else {
#pragma unroll
      for (int mi = 0; mi < 8; mi++)
#pragma unroll
        for (int ni = 0; ni < 4; ni++) {
          int e = bn * 256 + wn * 64 + ni * 16 + l15 - 4096;
          int hh = e >> 7, hd = e & 127;
          int m0 = bm * 256 + wm * 128 + mi * 16 + l4 * 4;
          int b = m0 >> 11, s0 = m0 & (SS - 1);
          u16x4 pk;
#pragma unroll
          for (int r = 0; r < 4; r++) pk[r] = f2bf(acc[mi][ni][r]);
          *(u16x4*)(Vt + (((long)(b * HH + hh) * 128 + hd) * SS + s0)) = pk;
        }
    }
  } else {
#pragma unroll
    for (int mi = 0; mi < 8; mi++)
#pragma unroll
      for (int ni = 0; ni < 4; ni++) {
        int n = bn * 256 + wn * 64 + ni * 16 + l15;
#pragma unroll
        for (int r = 0; r < 4; r++) {
          int m = bm * 256 + wm * 128 + mi * 16 + l4 * 4 + r;
          Cf[(long)m * N + n] = acc[mi][ni][r];
        }
      }
  }
}

// ---------------- causal flash attention (round-8, unchanged) ----------------
__global__ __launch_bounds__(256, 2) void attn_k(const __hip_bfloat16* __restrict__ qk,
                                                 const __hip_bfloat16* __restrict__ vt,
                                                 __hip_bfloat16* __restrict__ aout,
                                                 const int* __restrict__ posp) {
  __shared__ __hip_bfloat16 Ks[64 * 128];
  __shared__ __hip_bfloat16 Vs[128 * 64];
  __shared__ __hip_bfloat16 Ps[4][16 * 64];
  const int pos = *posp;
  const int orig = blockIdx.x;
  const int swz = (orig & 7) * 128 + (orig >> 3);
  const int qp = swz & 15, bh = swz >> 4;
  const int b = bh >> 4, h = bh & 15;
  const int tid = threadIdx.x;
  const int wave = tid >> 6, lane = tid & 63;
  const int l15 = lane & 15, l4 = lane >> 4;

  const long kbase = ((long)b * SS) * 4096 + 2048 + h * 128;
  const long vbase = ((long)bh * 128) * SS;
  const float sc2 = 0.08838834764831845f * 1.4426950408889634f;

  const int s_kr[4] = {(0 * 256 + tid) >> 4, (1 * 256 + tid) >> 4, (2 * 256 + tid) >> 4, (3 * 256 + tid) >> 4};
  const int s_kc = tid & 15;
  const int s_hd[4] = {(0 * 256 + tid) >> 3, (1 * 256 + tid) >> 3, (2 * 256 + tid) >> 3, (3 * 256 + tid) >> 3};
  const int s_vc = tid & 7;

  bf16x8 kreg[4], vreg[4];

#define LOADKV(T)                                                                             \
  {                                                                                           \
    const int kv0_ = (T) * 64;                                                                \
    _Pragma("unroll") for (int i = 0; i < 4; i++) {                                           \
      kreg[i] = *(const bf16x8*)(qk + kbase + (long)(kv0_ + s_kr[i]) * 4096 + s_kc * 8);      \
      vreg[i] = *(const bf16x8*)(vt + vbase + (long)s_hd[i] * SS + kv0_ + s_vc * 8);          \
    }                                                                                         \
  }

#define STAGE()                                                                               \
  {                                                                                           \
    _Pragma("unroll") for (int i = 0; i < 4; i++) {                                           \
      *(bf16x8*)(Ks + ((s_kr[i] * 128 + s_kc * 8) ^ ((s_kr[i] & 7) << 3))) = kreg[i];         \
      *(bf16x8*)(Vs + ((s_hd[i] * 64 + s_vc * 8) ^ ((s_hd[i] & 7) << 3))) = vreg[i];          \
    }                                                                                         \
  }

  for (int half = 0; half < 2; ++half) {
    const int qb = half ? (31 - qp) : qp;
    const int qwb = qb * 64 + wave * 16;

    bf16x8 qf[4];
#pragma unroll
    for (int kk = 0; kk < 4; kk++) {
      long row = (long)b * SS + qwb + l15;
      qf[kk] = *(const bf16x8*)(qk + row * 4096 + h * 128 + kk * 32 + l4 * 8);
    }

    f32x4 accO[8] = {};
    float mrun[4], lrun[4];
#pragma unroll
    for (int r = 0; r < 4; r++) { mrun[r] = MINIT; lrun[r] = 0.f; }

    int ntiles = (pos + qb * 64 + 63) / 64 + 1;
    if (ntiles > SS / 64) ntiles = SS / 64;
#define TT(t) (half ? (ntiles - 1 - (t)) : (t))

    LOADKV(TT(0));
    __syncthreads();
    STAGE();

    for (int t = 0; t < ntiles; ++t) {
      const int kv0 = TT(t) * 64;
      __syncthreads();
      if (t + 1 < ntiles) LOADKV(TT(t + 1));

      f32x4 sfr[4] = {};
      __builtin_amdgcn_s_setprio(1);
#pragma unroll
      for (int ni = 0; ni < 4; ni++) {
        const int key = ni * 16 + l15;
        const int sw = (key & 7) << 3;
#pragma unroll
        for (int kk = 0; kk < 4; kk++) {
          bf16x8 kf = *(const bf16x8*)(Ks + ((key * 128 + kk * 32 + l4 * 8) ^ sw));
          sfr[ni] = __builtin_amdgcn_mfma_f32_16x16x32_bf16(qf[kk], kf, sfr[ni], 0, 0, 0);
        }
      }
      __builtin_amdgcn_s_setprio(0);

      const bool needmask = (kv0 + 63) > (pos + qb * 64);
#pragma unroll
      for (int ni = 0; ni < 4; ni++)
#pragma unroll
        for (int r = 0; r < 4; r++) {
          float v = sfr[ni][r] * sc2;
          if (needmask) {
            int key = kv0 + ni * 16 + l15;
            int q = qwb + l4 * 4 + r;
            if (key > pos + q) v = MASKV;
          }
          sfr[ni][r] = v;
        }

      {
        f32x4 mx = sfr[0];
#pragma unroll
        for (int ni = 1; ni < 4; ni++)
#pragma unroll
          for (int r = 0; r < 4; r++) mx[r] = fmaxf(mx[r], sfr[ni][r]);
#pragma unroll
        for (int d = 1; d < 16; d <<= 1)
#pragma unroll
          for (int r = 0; r < 4; r++) mx[r] = fmaxf(mx[r], __shfl_xor(mx[r], d, 64));

        float growth = mx[0] - mrun[0];
#pragma unroll
        for (int r = 1; r < 4; r++) growth = fmaxf(growth, mx[r] - mrun[r]);
        if (!__all(growth <= 11.0f)) {
          float scal[4];
#pragma unroll
          for (int r = 0; r < 4; r++) {
            float mn = fmaxf(mrun[r], mx[r]);
            scal[r] = exp2f(mrun[r] - mn);
            mrun[r] = mn;
            lrun[r] *= scal[r];
          }
#pragma unroll
          for (int ni = 0; ni < 8; ni++)
#pragma unroll
            for (int r = 0; r < 4; r++) accO[ni][r] *= scal[r];
        }

        f32x4 rs = {0.f, 0.f, 0.f, 0.f};
#pragma unroll
        for (int ni = 0; ni < 4; ni++)
#pragma unroll
          for (int r = 0; r < 4; r++) {
            float p = exp2f(sfr[ni][r] - mrun[r]);
            rs[r] += p;
            int prow = l4 * 4 + r;
            Ps[wave][(prow * 64 + ni * 16 + l15) ^ ((prow & 7) << 3)] = __float2bfloat16(p);
          }
#pragma unroll
        for (int d = 1; d < 16; d <<= 1)
#pragma unroll
          for (int r = 0; r < 4; r++) rs[r] += __shfl_xor(rs[r], d, 64);
#pragma unroll
        for (int r = 0; r < 4; r++) lrun[r] += rs[r];
      }

      __builtin_amdgcn_s_setprio(1);
#pragma unroll
      for (int kk = 0; kk < 2; kk++) {
        int prow = l15;
        bf16x8 pf = *(const bf16x8*)(Ps[wave] + ((prow * 64 + kk * 32 + l4 * 8) ^ ((prow & 7) << 3)));
#pragma unroll
        for (int ni = 0; ni < 8; ni++) {
          int hd = ni * 16 + l15;
          bf16x8 vf = *(const bf16x8*)(Vs + ((hd * 64 + kk * 32 + l4 * 8) ^ ((hd & 7) << 3)));
          accO[ni] = __builtin_amdgcn_mfma_f32_16x16x32_bf16(pf, vf, accO[ni], 0, 0, 0);
        }
      }
      __builtin_amdgcn_s_setprio(0);

      __syncthreads();
      if (t + 1 < ntiles) STAGE();
    }
#undef TT

    __hip_bfloat16* E = Ks + wave * 2048;
    {
      float inv[4];
#pragma unroll
      for (int r = 0; r < 4; r++) inv[r] = 1.0f / lrun[r];
#pragma unroll
      for (int ni = 0; ni < 8; ni++)
#pragma unroll
        for (int r = 0; r < 4; r++) {
          int row = l4 * 4 + r;
          E[(row * 128 + ni * 16 + l15) ^ ((row & 7) << 3)] =
              __float2bfloat16(accO[ni][r] * inv[r]);
        }
    }
    const long gb = ((long)b * SS + qwb) * 2048 + h * 128;
#pragma unroll
    for (int j = 0; j < 4; j++) {
      int row = j * 4 + l4;
      int c8 = l15 * 8;
      bf16x8 v = *(const bf16x8*)(E + ((row * 128 + c8) ^ ((row & 7) << 3)));
      *(bf16x8*)(aout + gb + (long)row * 2048 + c8) = v;
    }
  }
#undef LOADKV
#undef STAGE
}

extern "C" void kernel_launch(void* const* d_in, const int* in_sizes, int n_in,
                              void* d_out, int out_size, void* d_ws, size_t ws_size,
                              hipStream_t stream) {
  (void)in_sizes; (void)n_in; (void)out_size; (void)ws_size;
  const float* h  = (const float*)d_in[0];
  const float* Wq = (const float*)d_in[1];
  const float* Wk = (const float*)d_in[2];
  const float* Wv = (const float*)d_in[3];
  const float* Wo = (const float*)d_in[4];
  const float* fc = (const float*)d_in[7];
  const float* fs = (const float*)d_in[8];
  const int* pos  = (const int*)d_in[9];
  float* out = (float*)d_out;

  char* ws = (char*)d_ws;
  __hip_bfloat16* hb    = (__hip_bfloat16*)(ws);                 // 33,554,432 B
  __hip_bfloat16* wqkv  = (__hip_bfloat16*)(ws + 33554432);      // 25,165,824 B
  __hip_bfloat16* wo_b  = (__hip_bfloat16*)(ws + 58720256);      //  8,388,608 B
  __hip_bfloat16* qkbuf = (__hip_bfloat16*)(ws + 67108864);      // 67,108,864 B
  __hip_bfloat16* vt    = (__hip_bfloat16*)(ws + 134217728);     // 33,554,432 B
  __hip_bfloat16* aout  = hb;  // alias: hb dead after GEMM1

  convertk<<<16384, 256, 0, stream>>>(h, hb, 4194304);
  convertk<<<4096, 256, 0, stream>>>(Wq, wqkv, 1048576);
  convertk<<<4096, 256, 0, stream>>>(Wk, wqkv + 4194304, 1048576);
  convertk<<<4096, 256, 0, stream>>>(Wv, wqkv + 8388608, 1048576);
  convertk<<<4096, 256, 0, stream>>>(Wo, wo_b, 1048576);

  // QKV projection + fused RoPE: M=8192, N=6144, K=2048  (32x24=768 blocks)
  gemm256<0><<<768, 512, 0, stream>>>(hb, wqkv, qkbuf, vt, nullptr, fc, fs, pos,
                                      8192, 6144, 2048);

  // causal flash attention (balanced, two-stream L2-local, 1024 blocks x 256 threads)
  attn_k<<<1024, 256, 0, stream>>>(qkbuf, vt, aout, pos);

  // output projection: M=8192, N=2048, K=2048 -> fp32 d_out  (32x8=256 blocks)
  gemm256<1><<<256, 512, 0, stream>>>(aout, wo_b, nullptr, nullptr, out, nullptr,
                                      nullptr, nullptr, 8192, 2048, 2048);
}

// Round 14
// 471.432 us; speedup vs baseline: 1.2987x; 1.2987x over previous
//
#include <hip/hip_runtime.h>
#include <hip/hip_bf16.h>

typedef __attribute__((ext_vector_type(8))) short bf16x8;
typedef __attribute__((ext_vector_type(4))) float f32x4;
typedef __attribute__((ext_vector_type(4))) unsigned short u16x4;

#define BB 4
#define SS 2048
#define DD 2048
#define HH 16
#define HDD 128
// QK buffer: [B*S][4096] bf16 (Q cols 0..2047, K cols 2048..4095), RoPE pre-applied
// Vt buffer: [B*H][128][2048] bf16 (V transposed: hd-major, s contiguous)
// Masking sentinels: finite so (masked) - (init) never yields exp2(0)=1.
#define MASKV (-30000.0f)
#define MINIT (-15000.0f)

__device__ __forceinline__ unsigned short f2bf(float f) {
  __hip_bfloat16 b = __float2bfloat16(f);
  return *reinterpret_cast<unsigned short*>(&b);
}
__device__ __forceinline__ void gl_lds16(const void* g, void* l) {
  __builtin_amdgcn_global_load_lds((const __attribute__((address_space(1))) unsigned int*)g,
                                   (__attribute__((address_space(3))) unsigned int*)l, 16, 0, 0);
}

// ---------------- fp32 -> bf16 conversion (vectorized) ----------------
__global__ __launch_bounds__(256) void convertk(const float* __restrict__ src,
                                                __hip_bfloat16* __restrict__ dst, int n4) {
  int i = blockIdx.x * 256 + threadIdx.x;
  if (i >= n4) return;
  f32x4 v = ((const f32x4*)src)[i];
  u16x4 o;
  o[0] = f2bf(v[0]); o[1] = f2bf(v[1]); o[2] = f2bf(v[2]); o[3] = f2bf(v[3]);
  ((u16x4*)dst)[i] = o;
}

// ---------------- 256x256 8-wave B^T GEMM, K-slice phases (ROUND-10 EXACT) ------
// Best-measured schedule: 221 us MODE-0, MfmaUtil 41%, 0 bank conflicts.
// BK=64, double-buffered 128KB LDS, XOR-swizzle (chunk ^= row&7) staged via
// inverse-swizzled global source. Per K-tile: 2 phases (k-slices of 32), each
// {12 ds_read_b128 (bg first) | stage 2 half-tiles of T+1 | barrier | 32 MFMA
// | barrier}; vmcnt(0) once per tile at phase 1. R11 (hoisted staging), R12
// (ring-4 counted vmcnt), R13 (phase-split BK=32) all measured WORSE (263/229/314)
// — this 2-barrier structure's ceiling is ~930 TF and this is its best point.
// MODE 0: epilogue -> QK buffer with fused RoPE (n<4096) or Vt (transposed).
// MODE 1: epilogue -> float C row-major [M][N].
template <int MODE>
__global__ __launch_bounds__(512, 1) void gemm256(const __hip_bfloat16* __restrict__ A,
                                                  const __hip_bfloat16* __restrict__ Bw,
                                                  __hip_bfloat16* __restrict__ Cbf,
                                                  __hip_bfloat16* __restrict__ Vt,
                                                  float* __restrict__ Cf,
                                                  const float* __restrict__ fc,
                                                  const float* __restrict__ fs,
                                                  const int* __restrict__ posp,
                                                  int M, int N, int K) {
  __shared__ __hip_bfloat16 As[2][2][128 * 64];  // [buf][half][row*64+col]  64KB
  __shared__ __hip_bfloat16 Bs[2][2][128 * 64];  // 64KB
  const int tid = threadIdx.x;
  const int wid = tid >> 6, lane = tid & 63;
  const int l15 = lane & 15, l4 = lane >> 4;
  const int wm = wid >> 2, wn = wid & 3;  // 2 x 4 wave grid; wave owns 128x64

  const int nbn = N >> 8;
  const int nb = (M >> 8) * nbn;
  const int bid = blockIdx.x;
  const int swz = (bid & 7) * (nb >> 3) + (bid >> 3);  // XCD-contiguous (nb%8==0)
  const int bm = swz / nbn, bn = swz % nbn;

  const int NT = K >> 6;  // K-tiles of 64

#define STAGE_HALF(Q, BUF, K0G)                                                   \
  {                                                                               \
    if ((Q) < 2) {                                                                \
      const long rowb = (long)bm * 256 + (Q) * 128;                               \
      _Pragma("unroll") for (int i = 0; i < 2; i++) {                             \
        int c = i * 512 + tid, rr = c >> 3, jj = (c & 7) ^ (rr & 7);              \
        gl_lds16(A + (rowb + rr) * (long)K + (K0G) + jj * 8,                      \
                 &As[BUF][(Q)][0] + c * 8);                                       \
      }                                                                           \
    } else {                                                                      \
      const long rowb = (long)bn * 256 + ((Q) - 2) * 128;                         \
      _Pragma("unroll") for (int i = 0; i < 2; i++) {                             \
        int c = i * 512 + tid, rr = c >> 3, jj = (c & 7) ^ (rr & 7);              \
        gl_lds16(Bw + (rowb + rr) * (long)K + (K0G) + jj * 8,                     \
                 &Bs[BUF][(Q) - 2][0] + c * 8);                                   \
      }                                                                           \
    }                                                                             \
  }

  f32x4 acc[8][4] = {};

  // prologue: tiles 0 and 1 fully staged
#pragma unroll
  for (int q = 0; q < 4; ++q) STAGE_HALF(q, 0, 0);
#pragma unroll
  for (int q = 0; q < 4; ++q) STAGE_HALF(q, 1, 64);
  __syncthreads();  // vmcnt(0)+lgkm(0)+barrier

  for (int T = 0; T < NT; ++T) {
    const int cur = T & 1;
    const int nxt = cur ^ 1;
    // buf[nxt] was consumed by tile T-1 (trailing barrier passed) -> staging
    // tile T+1 into it during tile T is race-free; read after T's vmcnt(0)+barrier.
    const bool do_stage = (T >= 1) && (T + 1 < NT);
    const int k0n = (T + 1) << 6;

#pragma unroll
    for (int k2 = 0; k2 < 2; ++k2) {
      // all fragments of this 32-wide k-slice, each read exactly once;
      // bg first: first MFMA depends on bg[0], lets fine-grained lgkm start early
      bf16x8 af[8], bg[4];
#pragma unroll
      for (int ni = 0; ni < 4; ni++) {
        int r = (wn & 1) * 64 + ni * 16 + l15;
        int j = (k2 * 4 + l4) ^ (r & 7);
        bg[ni] = *(const bf16x8*)(&Bs[cur][wn >> 1][0] + r * 64 + j * 8);
      }
#pragma unroll
      for (int mi = 0; mi < 8; mi++) {
        int r = mi * 16 + l15;
        int j = (k2 * 4 + l4) ^ (r & 7);
        af[mi] = *(const bf16x8*)(&As[cur][wm][0] + r * 64 + j * 8);
      }
      if (do_stage) {
        if (k2 == 0) { STAGE_HALF(0, nxt, k0n); STAGE_HALF(1, nxt, k0n); }
        else         { STAGE_HALF(2, nxt, k0n); STAGE_HALF(3, nxt, k0n); }
      }
      __builtin_amdgcn_s_barrier();
      asm volatile("" ::: "memory");
      __builtin_amdgcn_s_setprio(1);
#pragma unroll
      for (int mi = 0; mi < 8; mi++)
#pragma unroll
        for (int ni = 0; ni < 4; ni++)
          acc[mi][ni] = __builtin_amdgcn_mfma_f32_16x16x32_bf16(af[mi], bg[ni],
                                                                acc[mi][ni], 0, 0, 0);
      __builtin_amdgcn_s_setprio(0);
      if (k2 == 1) asm volatile("s_waitcnt vmcnt(0)" ::: "memory");
      __builtin_amdgcn_s_barrier();
      asm volatile("" ::: "memory");
    }
  }
#undef STAGE_HALF

  // ---- epilogue ----
  if (MODE == 0) {
    if (bn * 256 < 4096) {
      const int pos = *posp;
#pragma unroll
      for (int mi = 0; mi < 8; mi++)
#pragma unroll
        for (int ni = 0; ni < 4; ni++) {
          int n = bn * 256 + wn * 64 + ni * 16 + l15;
          int hd = n & 127;
          int ip = hd >> 1;
          bool odd = hd & 1;
#pragma unroll
          for (int r = 0; r < 4; r++) {
            float v = acc[mi][ni][r];
            float p = __shfl_xor(v, 1, 64);
            int m = bm * 256 + wm * 128 + mi * 16 + l4 * 4 + r;
            int s = m & (SS - 1);
            float cv = fc[(long)(pos + s) * 64 + ip];
            float sv = fs[(long)(pos + s) * 64 + ip];
            float out = odd ? (p * sv + v * cv) : (v * cv - p * sv);
            Cbf[(long)m * 4096 + n] = __float2bfloat16(out);
          }
        }
    } else {
#pragma unroll
      for (int mi = 0; mi < 8; mi++)
#pragma unroll
        for (int ni = 0; ni < 4; ni++) {
          int e = bn * 256 + wn * 64 + ni * 16 + l15 - 4096;
          int hh = e >> 7, hd = e & 127;
          int m0 = bm * 256 + wm * 128 + mi * 16 + l4 * 4;
          int b = m0 >> 11, s0 = m0 & (SS - 1);
          u16x4 pk;
#pragma unroll
          for (int r = 0; r < 4; r++) pk[r] = f2bf(acc[mi][ni][r]);
          *(u16x4*)(Vt + (((long)(b * HH + hh) * 128 + hd) * SS + s0)) = pk;
        }
    }
  } else {
#pragma unroll
    for (int mi = 0; mi < 8; mi++)
#pragma unroll
      for (int ni = 0; ni < 4; ni++) {
        int n = bn * 256 + wn * 64 + ni * 16 + l15;
#pragma unroll
        for (int r = 0; r < 4; r++) {
          int m = bm * 256 + wm * 128 + mi * 16 + l4 * 4 + r;
          Cf[(long)m * N + n] = acc[mi][ni][r];
        }
      }
  }
}

// ---------------- causal flash attention ----------------
// Round-8 structure + deferred lrun reduce: lrun is a PER-LANE partial sum
// (sum is linear; the defer-max rescale factor scal[r] is uniform across each
// 16-lane row-group since it derives from the group-reduced max), so the
// 16-lane shfl reduce happens ONCE per q-half instead of per KV tile —
// saves 16 shfl + 4 adds per tile on the serial softmax chain.
__global__ __launch_bounds__(256, 2) void attn_k(const __hip_bfloat16* __restrict__ qk,
                                                 const __hip_bfloat16* __restrict__ vt,
                                                 __hip_bfloat16* __restrict__ aout,
                                                 const int* __restrict__ posp) {
  __shared__ __hip_bfloat16 Ks[64 * 128];
  __shared__ __hip_bfloat16 Vs[128 * 64];
  __shared__ __hip_bfloat16 Ps[4][16 * 64];
  const int pos = *posp;
  const int orig = blockIdx.x;
  const int swz = (orig & 7) * 128 + (orig >> 3);
  const int qp = swz & 15, bh = swz >> 4;
  const int b = bh >> 4, h = bh & 15;
  const int tid = threadIdx.x;
  const int wave = tid >> 6, lane = tid & 63;
  const int l15 = lane & 15, l4 = lane >> 4;

  const long kbase = ((long)b * SS) * 4096 + 2048 + h * 128;
  const long vbase = ((long)bh * 128) * SS;
  const float sc2 = 0.08838834764831845f * 1.4426950408889634f;

  const int s_kr[4] = {(0 * 256 + tid) >> 4, (1 * 256 + tid) >> 4, (2 * 256 + tid) >> 4, (3 * 256 + tid) >> 4};
  const int s_kc = tid & 15;
  const int s_hd[4] = {(0 * 256 + tid) >> 3, (1 * 256 + tid) >> 3, (2 * 256 + tid) >> 3, (3 * 256 + tid) >> 3};
  const int s_vc = tid & 7;

  bf16x8 kreg[4], vreg[4];

#define LOADKV(T)                                                                             \
  {                                                                                           \
    const int kv0_ = (T) * 64;                                                                \
    _Pragma("unroll") for (int i = 0; i < 4; i++) {                                           \
      kreg[i] = *(const bf16x8*)(qk + kbase + (long)(kv0_ + s_kr[i]) * 4096 + s_kc * 8);      \
      vreg[i] = *(const bf16x8*)(vt + vbase + (long)s_hd[i] * SS + kv0_ + s_vc * 8);          \
    }                                                                                         \
  }

#define STAGE()                                                                               \
  {                                                                                           \
    _Pragma("unroll") for (int i = 0; i < 4; i++) {                                           \
      *(bf16x8*)(Ks + ((s_kr[i] * 128 + s_kc * 8) ^ ((s_kr[i] & 7) << 3))) = kreg[i];         \
      *(bf16x8*)(Vs + ((s_hd[i] * 64 + s_vc * 8) ^ ((s_hd[i] & 7) << 3))) = vreg[i];          \
    }                                                                                         \
  }

  for (int half = 0; half < 2; ++half) {
    const int qb = half ? (31 - qp) : qp;
    const int qwb = qb * 64 + wave * 16;

    bf16x8 qf[4];
#pragma unroll
    for (int kk = 0; kk < 4; kk++) {
      long row = (long)b * SS + qwb + l15;
      qf[kk] = *(const bf16x8*)(qk + row * 4096 + h * 128 + kk * 32 + l4 * 8);
    }

    f32x4 accO[8] = {};
    float mrun[4], lrun[4];
#pragma unroll
    for (int r = 0; r < 4; r++) { mrun[r] = MINIT; lrun[r] = 0.f; }

    int ntiles = (pos + qb * 64 + 63) / 64 + 1;
    if (ntiles > SS / 64) ntiles = SS / 64;
#define TT(t) (half ? (ntiles - 1 - (t)) : (t))

    LOADKV(TT(0));
    __syncthreads();
    STAGE();

    for (int t = 0; t < ntiles; ++t) {
      const int kv0 = TT(t) * 64;
      __syncthreads();
      if (t + 1 < ntiles) LOADKV(TT(t + 1));

      f32x4 sfr[4] = {};
      __builtin_amdgcn_s_setprio(1);
#pragma unroll
      for (int ni = 0; ni < 4; ni++) {
        const int key = ni * 16 + l15;
        const int sw = (key & 7) << 3;
#pragma unroll
        for (int kk = 0; kk < 4; kk++) {
          bf16x8 kf = *(const bf16x8*)(Ks + ((key * 128 + kk * 32 + l4 * 8) ^ sw));
          sfr[ni] = __builtin_amdgcn_mfma_f32_16x16x32_bf16(qf[kk], kf, sfr[ni], 0, 0, 0);
        }
      }
      __builtin_amdgcn_s_setprio(0);

      const bool needmask = (kv0 + 63) > (pos + qb * 64);
#pragma unroll
      for (int ni = 0; ni < 4; ni++)
#pragma unroll
        for (int r = 0; r < 4; r++) {
          float v = sfr[ni][r] * sc2;
          if (needmask) {
            int key = kv0 + ni * 16 + l15;
            int q = qwb + l4 * 4 + r;
            if (key > pos + q) v = MASKV;
          }
          sfr[ni][r] = v;
        }

      {
        f32x4 mx = sfr[0];
#pragma unroll
        for (int ni = 1; ni < 4; ni++)
#pragma unroll
          for (int r = 0; r < 4; r++) mx[r] = fmaxf(mx[r], sfr[ni][r]);
#pragma unroll
        for (int d = 1; d < 16; d <<= 1)
#pragma unroll
          for (int r = 0; r < 4; r++) mx[r] = fmaxf(mx[r], __shfl_xor(mx[r], d, 64));

        float growth = mx[0] - mrun[0];
#pragma unroll
        for (int r = 1; r < 4; r++) growth = fmaxf(growth, mx[r] - mrun[r]);
        if (!__all(growth <= 11.0f)) {
          float scal[4];
#pragma unroll
          for (int r = 0; r < 4; r++) {
            float mn = fmaxf(mrun[r], mx[r]);
            scal[r] = exp2f(mrun[r] - mn);
            mrun[r] = mn;
            lrun[r] *= scal[r];   // uniform scal across the 16-lane group:
          }                        // valid on per-lane partials
#pragma unroll
          for (int ni = 0; ni < 8; ni++)
#pragma unroll
            for (int r = 0; r < 4; r++) accO[ni][r] *= scal[r];
        }

        // per-lane partial sum only; cross-lane reduce deferred to epilogue
#pragma unroll
        for (int ni = 0; ni < 4; ni++)
#pragma unroll
          for (int r = 0; r < 4; r++) {
            float p = exp2f(sfr[ni][r] - mrun[r]);
            lrun[r] += p;
            int prow = l4 * 4 + r;
            Ps[wave][(prow * 64 + ni * 16 + l15) ^ ((prow & 7) << 3)] = __float2bfloat16(p);
          }
      }

      __builtin_amdgcn_s_setprio(1);
#pragma unroll
      for (int kk = 0; kk < 2; kk++) {
        int prow = l15;
        bf16x8 pf = *(const bf16x8*)(Ps[wave] + ((prow * 64 + kk * 32 + l4 * 8) ^ ((prow & 7) << 3)));
#pragma unroll
        for (int ni = 0; ni < 8; ni++) {
          int hd = ni * 16 + l15;
          bf16x8 vf = *(const bf16x8*)(Vs + ((hd * 64 + kk * 32 + l4 * 8) ^ ((hd & 7) << 3)));
          accO[ni] = __builtin_amdgcn_mfma_f32_16x16x32_bf16(pf, vf, accO[ni], 0, 0, 0);
        }
      }
      __builtin_amdgcn_s_setprio(0);

      __syncthreads();
      if (t + 1 < ntiles) STAGE();
    }
#undef TT

    // deferred cross-lane lrun reduce (once per q-half)
#pragma unroll
    for (int d = 1; d < 16; d <<= 1)
#pragma unroll
      for (int r = 0; r < 4; r++) lrun[r] += __shfl_xor(lrun[r], d, 64);

    __hip_bfloat16* E = Ks + wave * 2048;
    {
      float inv[4];
#pragma unroll
      for (int r = 0; r < 4; r++) inv[r] = 1.0f / lrun[r];
#pragma unroll
      for (int ni = 0; ni < 8; ni++)
#pragma unroll
        for (int r = 0; r < 4; r++) {
          int row = l4 * 4 + r;
          E[(row * 128 + ni * 16 + l15) ^ ((row & 7) << 3)] =
              __float2bfloat16(accO[ni][r] * inv[r]);
        }
    }
    const long gb = ((long)b * SS + qwb) * 2048 + h * 128;
#pragma unroll
    for (int j = 0; j < 4; j++) {
      int row = j * 4 + l4;
      int c8 = l15 * 8;
      bf16x8 v = *(const bf16x8*)(E + ((row * 128 + c8) ^ ((row & 7) << 3)));
      *(bf16x8*)(aout + gb + (long)row * 2048 + c8) = v;
    }
  }
#undef LOADKV
#undef STAGE
}

extern "C" void kernel_launch(void* const* d_in, const int* in_sizes, int n_in,
                              void* d_out, int out_size, void* d_ws, size_t ws_size,
                              hipStream_t stream) {
  (void)in_sizes; (void)n_in; (void)out_size; (void)ws_size;
  const float* h  = (const float*)d_in[0];
  const float* Wq = (const float*)d_in[1];
  const float* Wk = (const float*)d_in[2];
  const float* Wv = (const float*)d_in[3];
  const float* Wo = (const float*)d_in[4];
  const float* fc = (const float*)d_in[7];
  const float* fs = (const float*)d_in[8];
  const int* pos  = (const int*)d_in[9];
  float* out = (float*)d_out;

  char* ws = (char*)d_ws;
  __hip_bfloat16* hb    = (__hip_bfloat16*)(ws);                 // 33,554,432 B
  __hip_bfloat16* wqkv  = (__hip_bfloat16*)(ws + 33554432);      // 25,165,824 B
  __hip_bfloat16* wo_b  = (__hip_bfloat16*)(ws + 58720256);      //  8,388,608 B
  __hip_bfloat16* qkbuf = (__hip_bfloat16*)(ws + 67108864);      // 67,108,864 B
  __hip_bfloat16* vt    = (__hip_bfloat16*)(ws + 134217728);     // 33,554,432 B
  __hip_bfloat16* aout  = hb;  // alias: hb dead after GEMM1

  convertk<<<16384, 256, 0, stream>>>(h, hb, 4194304);
  convertk<<<4096, 256, 0, stream>>>(Wq, wqkv, 1048576);
  convertk<<<4096, 256, 0, stream>>>(Wk, wqkv + 4194304, 1048576);
  convertk<<<4096, 256, 0, stream>>>(Wv, wqkv + 8388608, 1048576);
  convertk<<<4096, 256, 0, stream>>>(Wo, wo_b, 1048576);

  // QKV projection + fused RoPE: M=8192, N=6144, K=2048  (32x24=768 blocks)
  gemm256<0><<<768, 512, 0, stream>>>(hb, wqkv, qkbuf, vt, nullptr, fc, fs, pos,
                                      8192, 6144, 2048);

  // causal flash attention (balanced, two-stream L2-local, 1024 blocks x 256 threads)
  attn_k<<<1024, 256, 0, stream>>>(qkbuf, vt, aout, pos);

  // output projection: M=8192, N=2048, K=2048 -> fp32 d_out  (32x8=256 blocks)
  gemm256<1><<<256, 512, 0, stream>>>(aout, wo_b, nullptr, nullptr, out, nullptr,
                                      nullptr, nullptr, 8192, 2048, 2048);
}

// Round 15
// 463.534 us; speedup vs baseline: 1.3209x; 1.0170x over previous
//
#include <hip/hip_runtime.h>
#include <hip/hip_bf16.h>

typedef __attribute__((ext_vector_type(8))) short bf16x8;
typedef __attribute__((ext_vector_type(4))) float f32x4;
typedef __attribute__((ext_vector_type(4))) unsigned short u16x4;

#define BB 4
#define SS 2048
#define DD 2048
#define HH 16
#define HDD 128
// QK buffer: [B*S][4096] bf16 (Q cols 0..2047, K cols 2048..4095), RoPE pre-applied
// Vt buffer: [B*H][128][2048] bf16 (V transposed: hd-major, s contiguous)
// Masking sentinels: finite so (masked) - (init) never yields exp2(0)=1.
#define MASKV (-30000.0f)
#define MINIT (-15000.0f)

__device__ __forceinline__ unsigned short f2bf(float f) {
  __hip_bfloat16 b = __float2bfloat16(f);
  return *reinterpret_cast<unsigned short*>(&b);
}
__device__ __forceinline__ void gl_lds16(const void* g, void* l) {
  __builtin_amdgcn_global_load_lds((const __attribute__((address_space(1))) unsigned int*)g,
                                   (__attribute__((address_space(3))) unsigned int*)l, 16, 0, 0);
}

// ---------------- fused fp32 -> bf16 conversion (single launch, 5 segments) ----
// Segment sizes are exact multiples of 256 float4s -> branch-free bounds.
// blocks: [0,16384) h | [16384,20480) Wq | [20480,24576) Wk
//         [24576,28672) Wv | [28672,32768) Wo
__global__ __launch_bounds__(256) void convert_all(const float* __restrict__ h,
                                                   const float* __restrict__ Wq,
                                                   const float* __restrict__ Wk,
                                                   const float* __restrict__ Wv,
                                                   const float* __restrict__ Wo,
                                                   __hip_bfloat16* __restrict__ hb,
                                                   __hip_bfloat16* __restrict__ wqkv,
                                                   __hip_bfloat16* __restrict__ wo_b) {
  int blk = blockIdx.x;
  const float* src;
  __hip_bfloat16* dst;
  int base;
  if (blk < 16384)      { src = h;  dst = hb;             base = 0; }
  else if (blk < 20480) { src = Wq; dst = wqkv;           base = 16384; }
  else if (blk < 24576) { src = Wk; dst = wqkv + 4194304; base = 20480; }
  else if (blk < 28672) { src = Wv; dst = wqkv + 8388608; base = 24576; }
  else                  { src = Wo; dst = wo_b;           base = 28672; }
  int i = (blk - base) * 256 + threadIdx.x;
  f32x4 v = ((const f32x4*)src)[i];
  u16x4 o;
  o[0] = f2bf(v[0]); o[1] = f2bf(v[1]); o[2] = f2bf(v[2]); o[3] = f2bf(v[3]);
  ((u16x4*)dst)[i] = o;
}

// ---------------- 256x256 8-wave B^T GEMM, K-slice phases (ROUND-10 EXACT) ------
// Best-measured schedule: 221 us MODE-0, MfmaUtil 41%, 0 bank conflicts (932 TF =
// the documented ~930 TF 2-barrier-structure ceiling). BK=64, double-buffered
// 128KB LDS, XOR-swizzle (chunk ^= row&7) staged via inverse-swizzled global
// source. Per K-tile: 2 phases (k-slices of 32), each {12 ds_read_b128 (bg first)
// | stage 2 half-tiles of T+1 | barrier | 32 MFMA | barrier}; vmcnt(0) once per
// tile. Deep-pipeline variants measured WORSE: R11 hoisted 263, R12 ring-4
// counted 229, R13 phase-split 314. Cross-wave LDS visibility at the tile
// barrier forces the per-tile drain at this staging granularity.
// MODE 0: epilogue -> QK buffer with fused RoPE (n<4096) or Vt (transposed).
// MODE 1: epilogue -> float C row-major [M][N].
template <int MODE>
__global__ __launch_bounds__(512, 1) void gemm256(const __hip_bfloat16* __restrict__ A,
                                                  const __hip_bfloat16* __restrict__ Bw,
                                                  __hip_bfloat16* __restrict__ Cbf,
                                                  __hip_bfloat16* __restrict__ Vt,
                                                  float* __restrict__ Cf,
                                                  const float* __restrict__ fc,
                                                  const float* __restrict__ fs,
                                                  const int* __restrict__ posp,
                                                  int M, int N, int K) {
  __shared__ __hip_bfloat16 As[2][2][128 * 64];  // [buf][half][row*64+col]  64KB
  __shared__ __hip_bfloat16 Bs[2][2][128 * 64];  // 64KB
  const int tid = threadIdx.x;
  const int wid = tid >> 6, lane = tid & 63;
  const int l15 = lane & 15, l4 = lane >> 4;
  const int wm = wid >> 2, wn = wid & 3;  // 2 x 4 wave grid; wave owns 128x64

  const int nbn = N >> 8;
  const int nb = (M >> 8) * nbn;
  const int bid = blockIdx.x;
  const int swz = (bid & 7) * (nb >> 3) + (bid >> 3);  // XCD-contiguous (nb%8==0)
  const int bm = swz / nbn, bn = swz % nbn;

  const int NT = K >> 6;  // K-tiles of 64

#define STAGE_HALF(Q, BUF, K0G)                                                   \
  {                                                                               \
    if ((Q) < 2) {                                                                \
      const long rowb = (long)bm * 256 + (Q) * 128;                               \
      _Pragma("unroll") for (int i = 0; i < 2; i++) {                             \
        int c = i * 512 + tid, rr = c >> 3, jj = (c & 7) ^ (rr & 7);              \
        gl_lds16(A + (rowb + rr) * (long)K + (K0G) + jj * 8,                      \
                 &As[BUF][(Q)][0] + c * 8);                                       \
      }                                                                           \
    } else {                                                                      \
      const long rowb = (long)bn * 256 + ((Q) - 2) * 128;                         \
      _Pragma("unroll") for (int i = 0; i < 2; i++) {                             \
        int c = i * 512 + tid, rr = c >> 3, jj = (c & 7) ^ (rr & 7);              \
        gl_lds16(Bw + (rowb + rr) * (long)K + (K0G) + jj * 8,                     \
                 &Bs[BUF][(Q) - 2][0] + c * 8);                                   \
      }                                                                           \
    }                                                                             \
  }

  f32x4 acc[8][4] = {};

  // prologue: tiles 0 and 1 fully staged
#pragma unroll
  for (int q = 0; q < 4; ++q) STAGE_HALF(q, 0, 0);
#pragma unroll
  for (int q = 0; q < 4; ++q) STAGE_HALF(q, 1, 64);
  __syncthreads();  // vmcnt(0)+lgkm(0)+barrier

  for (int T = 0; T < NT; ++T) {
    const int cur = T & 1;
    const int nxt = cur ^ 1;
    // buf[nxt] was consumed by tile T-1 (trailing barrier passed) -> staging
    // tile T+1 into it during tile T is race-free; read after T's vmcnt(0)+barrier.
    const bool do_stage = (T >= 1) && (T + 1 < NT);
    const int k0n = (T + 1) << 6;

#pragma unroll
    for (int k2 = 0; k2 < 2; ++k2) {
      // all fragments of this 32-wide k-slice, each read exactly once;
      // bg first: first MFMA depends on bg[0], lets fine-grained lgkm start early
      bf16x8 af[8], bg[4];
#pragma unroll
      for (int ni = 0; ni < 4; ni++) {
        int r = (wn & 1) * 64 + ni * 16 + l15;
        int j = (k2 * 4 + l4) ^ (r & 7);
        bg[ni] = *(const bf16x8*)(&Bs[cur][wn >> 1][0] + r * 64 + j * 8);
      }
#pragma unroll
      for (int mi = 0; mi < 8; mi++) {
        int r = mi * 16 + l15;
        int j = (k2 * 4 + l4) ^ (r & 7);
        af[mi] = *(const bf16x8*)(&As[cur][wm][0] + r * 64 + j * 8);
      }
      if (do_stage) {
        if (k2 == 0) { STAGE_HALF(0, nxt, k0n); STAGE_HALF(1, nxt, k0n); }
        else         { STAGE_HALF(2, nxt, k0n); STAGE_HALF(3, nxt, k0n); }
      }
      __builtin_amdgcn_s_barrier();
      asm volatile("" ::: "memory");
      __builtin_amdgcn_s_setprio(1);
#pragma unroll
      for (int mi = 0; mi < 8; mi++)
#pragma unroll
        for (int ni = 0; ni < 4; ni++)
          acc[mi][ni] = __builtin_amdgcn_mfma_f32_16x16x32_bf16(af[mi], bg[ni],
                                                                acc[mi][ni], 0, 0, 0);
      __builtin_amdgcn_s_setprio(0);
      if (k2 == 1) asm volatile("s_waitcnt vmcnt(0)" ::: "memory");
      __builtin_amdgcn_s_barrier();
      asm volatile("" ::: "memory");
    }
  }
#undef STAGE_HALF

  // ---- epilogue ----
  if (MODE == 0) {
    if (bn * 256 < 4096) {
      const int pos = *posp;
#pragma unroll
      for (int mi = 0; mi < 8; mi++)
#pragma unroll
        for (int ni = 0; ni < 4; ni++) {
          int n = bn * 256 + wn * 64 + ni * 16 + l15;
          int hd = n & 127;
          int ip = hd >> 1;
          bool odd = hd & 1;
#pragma unroll
          for (int r = 0; r < 4; r++) {
            float v = acc[mi][ni][r];
            float p = __shfl_xor(v, 1, 64);
            int m = bm * 256 + wm * 128 + mi * 16 + l4 * 4 + r;
            int s = m & (SS - 1);
            float cv = fc[(long)(pos + s) * 64 + ip];
            float sv = fs[(long)(pos + s) * 64 + ip];
            float out = odd ? (p * sv + v * cv) : (v * cv - p * sv);
            Cbf[(long)m * 4096 + n] = __float2bfloat16(out);
          }
        }
    } else {
#pragma unroll
      for (int mi = 0; mi < 8; mi++)
#pragma unroll
        for (int ni = 0; ni < 4; ni++) {
          int e = bn * 256 + wn * 64 + ni * 16 + l15 - 4096;
          int hh = e >> 7, hd = e & 127;
          int m0 = bm * 256 + wm * 128 + mi * 16 + l4 * 4;
          int b = m0 >> 11, s0 = m0 & (SS - 1);
          u16x4 pk;
#pragma unroll
          for (int r = 0; r < 4; r++) pk[r] = f2bf(acc[mi][ni][r]);
          *(u16x4*)(Vt + (((long)(b * HH + hh) * 128 + hd) * SS + s0)) = pk;
        }
    }
  } else {
#pragma unroll
    for (int mi = 0; mi < 8; mi++)
#pragma unroll
      for (int ni = 0; ni < 4; ni++) {
        int n = bn * 256 + wn * 64 + ni * 16 + l15;
#pragma unroll
        for (int r = 0; r < 4; r++) {
          int m = bm * 256 + wm * 128 + mi * 16 + l4 * 4 + r;
          Cf[(long)m * N + n] = acc[mi][ni][r];
        }
      }
  }
}

// ---------------- causal flash attention (round-14, unchanged) ----------------
// Two-stream balanced sweep + single-buffer LDS with reg prefetch + defer-max
// (finite sentinels) + per-lane deferred lrun reduce + coalesced epilogue.
__global__ __launch_bounds__(256, 2) void attn_k(const __hip_bfloat16* __restrict__ qk,
                                                 const __hip_bfloat16* __restrict__ vt,
                                                 __hip_bfloat16* __restrict__ aout,
                                                 const int* __restrict__ posp) {
  __shared__ __hip_bfloat16 Ks[64 * 128];
  __shared__ __hip_bfloat16 Vs[128 * 64];
  __shared__ __hip_bfloat16 Ps[4][16 * 64];
  const int pos = *posp;
  const int orig = blockIdx.x;
  const int swz = (orig & 7) * 128 + (orig >> 3);
  const int qp = swz & 15, bh = swz >> 4;
  const int b = bh >> 4, h = bh & 15;
  const int tid = threadIdx.x;
  const int wave = tid >> 6, lane = tid & 63;
  const int l15 = lane & 15, l4 = lane >> 4;

  const long kbase = ((long)b * SS) * 4096 + 2048 + h * 128;
  const long vbase = ((long)bh * 128) * SS;
  const float sc2 = 0.08838834764831845f * 1.4426950408889634f;

  const int s_kr[4] = {(0 * 256 + tid) >> 4, (1 * 256 + tid) >> 4, (2 * 256 + tid) >> 4, (3 * 256 + tid) >> 4};
  const int s_kc = tid & 15;
  const int s_hd[4] = {(0 * 256 + tid) >> 3, (1 * 256 + tid) >> 3, (2 * 256 + tid) >> 3, (3 * 256 + tid) >> 3};
  const int s_vc = tid & 7;

  bf16x8 kreg[4], vreg[4];

#define LOADKV(T)                                                                             \
  {                                                                                           \
    const int kv0_ = (T) * 64;                                                                \
    _Pragma("unroll") for (int i = 0; i < 4; i++) {                                           \
      kreg[i] = *(const bf16x8*)(qk + kbase + (long)(kv0_ + s_kr[i]) * 4096 + s_kc * 8);      \
      vreg[i] = *(const bf16x8*)(vt + vbase + (long)s_hd[i] * SS + kv0_ + s_vc * 8);          \
    }                                                                                         \
  }

#define STAGE()                                                                               \
  {                                                                                           \
    _Pragma("unroll") for (int i = 0; i < 4; i++) {                                           \
      *(bf16x8*)(Ks + ((s_kr[i] * 128 + s_kc * 8) ^ ((s_kr[i] & 7) << 3))) = kreg[i];         \
      *(bf16x8*)(Vs + ((s_hd[i] * 64 + s_vc * 8) ^ ((s_hd[i] & 7) << 3))) = vreg[i];          \
    }                                                                                         \
  }

  for (int half = 0; half < 2; ++half) {
    const int qb = half ? (31 - qp) : qp;
    const int qwb = qb * 64 + wave * 16;

    bf16x8 qf[4];
#pragma unroll
    for (int kk = 0; kk < 4; kk++) {
      long row = (long)b * SS + qwb + l15;
      qf[kk] = *(const bf16x8*)(qk + row * 4096 + h * 128 + kk * 32 + l4 * 8);
    }

    f32x4 accO[8] = {};
    float mrun[4], lrun[4];
#pragma unroll
    for (int r = 0; r < 4; r++) { mrun[r] = MINIT; lrun[r] = 0.f; }

    int ntiles = (pos + qb * 64 + 63) / 64 + 1;
    if (ntiles > SS / 64) ntiles = SS / 64;
#define TT(t) (half ? (ntiles - 1 - (t)) : (t))

    LOADKV(TT(0));
    __syncthreads();
    STAGE();

    for (int t = 0; t < ntiles; ++t) {
      const int kv0 = TT(t) * 64;
      __syncthreads();
      if (t + 1 < ntiles) LOADKV(TT(t + 1));

      f32x4 sfr[4] = {};
      __builtin_amdgcn_s_setprio(1);
#pragma unroll
      for (int ni = 0; ni < 4; ni++) {
        const int key = ni * 16 + l15;
        const int sw = (key & 7) << 3;
#pragma unroll
        for (int kk = 0; kk < 4; kk++) {
          bf16x8 kf = *(const bf16x8*)(Ks + ((key * 128 + kk * 32 + l4 * 8) ^ sw));
          sfr[ni] = __builtin_amdgcn_mfma_f32_16x16x32_bf16(qf[kk], kf, sfr[ni], 0, 0, 0);
        }
      }
      __builtin_amdgcn_s_setprio(0);

      const bool needmask = (kv0 + 63) > (pos + qb * 64);
#pragma unroll
      for (int ni = 0; ni < 4; ni++)
#pragma unroll
        for (int r = 0; r < 4; r++) {
          float v = sfr[ni][r] * sc2;
          if (needmask) {
            int key = kv0 + ni * 16 + l15;
            int q = qwb + l4 * 4 + r;
            if (key > pos + q) v = MASKV;
          }
          sfr[ni][r] = v;
        }

      {
        f32x4 mx = sfr[0];
#pragma unroll
        for (int ni = 1; ni < 4; ni++)
#pragma unroll
          for (int r = 0; r < 4; r++) mx[r] = fmaxf(mx[r], sfr[ni][r]);
#pragma unroll
        for (int d = 1; d < 16; d <<= 1)
#pragma unroll
          for (int r = 0; r < 4; r++) mx[r] = fmaxf(mx[r], __shfl_xor(mx[r], d, 64));

        float growth = mx[0] - mrun[0];
#pragma unroll
        for (int r = 1; r < 4; r++) growth = fmaxf(growth, mx[r] - mrun[r]);
        if (!__all(growth <= 11.0f)) {
          float scal[4];
#pragma unroll
          for (int r = 0; r < 4; r++) {
            float mn = fmaxf(mrun[r], mx[r]);
            scal[r] = exp2f(mrun[r] - mn);
            mrun[r] = mn;
            lrun[r] *= scal[r];   // scal uniform across 16-lane group: valid on partials
          }
#pragma unroll
          for (int ni = 0; ni < 8; ni++)
#pragma unroll
            for (int r = 0; r < 4; r++) accO[ni][r] *= scal[r];
        }

        // per-lane partial sum; cross-lane reduce deferred to epilogue
#pragma unroll
        for (int ni = 0; ni < 4; ni++)
#pragma unroll
          for (int r = 0; r < 4; r++) {
            float p = exp2f(sfr[ni][r] - mrun[r]);
            lrun[r] += p;
            int prow = l4 * 4 + r;
            Ps[wave][(prow * 64 + ni * 16 + l15) ^ ((prow & 7) << 3)] = __float2bfloat16(p);
          }
      }

      __builtin_amdgcn_s_setprio(1);
#pragma unroll
      for (int kk = 0; kk < 2; kk++) {
        int prow = l15;
        bf16x8 pf = *(const bf16x8*)(Ps[wave] + ((prow * 64 + kk * 32 + l4 * 8) ^ ((prow & 7) << 3)));
#pragma unroll
        for (int ni = 0; ni < 8; ni++) {
          int hd = ni * 16 + l15;
          bf16x8 vf = *(const bf16x8*)(Vs + ((hd * 64 + kk * 32 + l4 * 8) ^ ((hd & 7) << 3)));
          accO[ni] = __builtin_amdgcn_mfma_f32_16x16x32_bf16(pf, vf, accO[ni], 0, 0, 0);
        }
      }
      __builtin_amdgcn_s_setprio(0);

      __syncthreads();
      if (t + 1 < ntiles) STAGE();
    }
#undef TT

    // deferred cross-lane lrun reduce (once per q-half)
#pragma unroll
    for (int d = 1; d < 16; d <<= 1)
#pragma unroll
      for (int r = 0; r < 4; r++) lrun[r] += __shfl_xor(lrun[r], d, 64);

    __hip_bfloat16* E = Ks + wave * 2048;
    {
      float inv[4];
#pragma unroll
      for (int r = 0; r < 4; r++) inv[r] = 1.0f / lrun[r];
#pragma unroll
      for (int ni = 0; ni < 8; ni++)
#pragma unroll
        for (int r = 0; r < 4; r++) {
          int row = l4 * 4 + r;
          E[(row * 128 + ni * 16 + l15) ^ ((row & 7) << 3)] =
              __float2bfloat16(accO[ni][r] * inv[r]);
        }
    }
    const long gb = ((long)b * SS + qwb) * 2048 + h * 128;
#pragma unroll
    for (int j = 0; j < 4; j++) {
      int row = j * 4 + l4;
      int c8 = l15 * 8;
      bf16x8 v = *(const bf16x8*)(E + ((row * 128 + c8) ^ ((row & 7) << 3)));
      *(bf16x8*)(aout + gb + (long)row * 2048 + c8) = v;
    }
  }
#undef LOADKV
#undef STAGE
}

extern "C" void kernel_launch(void* const* d_in, const int* in_sizes, int n_in,
                              void* d_out, int out_size, void* d_ws, size_t ws_size,
                              hipStream_t stream) {
  (void)in_sizes; (void)n_in; (void)out_size; (void)ws_size;
  const float* h  = (const float*)d_in[0];
  const float* Wq = (const float*)d_in[1];
  const float* Wk = (const float*)d_in[2];
  const float* Wv = (const float*)d_in[3];
  const float* Wo = (const float*)d_in[4];
  const float* fc = (const float*)d_in[7];
  const float* fs = (const float*)d_in[8];
  const int* pos  = (const int*)d_in[9];
  float* out = (float*)d_out;

  char* ws = (char*)d_ws;
  __hip_bfloat16* hb    = (__hip_bfloat16*)(ws);                 // 33,554,432 B
  __hip_bfloat16* wqkv  = (__hip_bfloat16*)(ws + 33554432);      // 25,165,824 B
  __hip_bfloat16* wo_b  = (__hip_bfloat16*)(ws + 58720256);      //  8,388,608 B
  __hip_bfloat16* qkbuf = (__hip_bfloat16*)(ws + 67108864);      // 67,108,864 B
  __hip_bfloat16* vt    = (__hip_bfloat16*)(ws + 134217728);     // 33,554,432 B
  __hip_bfloat16* aout  = hb;  // alias: hb dead after GEMM1

  // fused fp32 -> bf16 (h + Wq + Wk + Wv + Wo), single launch
  convert_all<<<32768, 256, 0, stream>>>(h, Wq, Wk, Wv, Wo, hb, wqkv, wo_b);

  // QKV projection + fused RoPE: M=8192, N=6144, K=2048  (32x24=768 blocks)
  gemm256<0><<<768, 512, 0, stream>>>(hb, wqkv, qkbuf, vt, nullptr, fc, fs, pos,
                                      8192, 6144, 2048);

  // causal flash attention (balanced, two-stream L2-local, 1024 blocks x 256 threads)
  attn_k<<<1024, 256, 0, stream>>>(qkbuf, vt, aout, pos);

  // output projection: M=8192, N=2048, K=2048 -> fp32 d_out  (32x8=256 blocks)
  gemm256<1><<<256, 512, 0, stream>>>(aout, wo_b, nullptr, nullptr, out, nullptr,
                                      nullptr, nullptr, 8192, 2048, 2048);
}

// Round 16
// 458.242 us; speedup vs baseline: 1.3361x; 1.0115x over previous
//
#include <hip/hip_runtime.h>
#include <hip/hip_bf16.h>

typedef __attribute__((ext_vector_type(8))) short bf16x8;
typedef __attribute__((ext_vector_type(4))) float f32x4;
typedef __attribute__((ext_vector_type(4))) unsigned short u16x4;

#define BB 4
#define SS 2048
#define DD 2048
#define HH 16
#define HDD 128
// QK buffer: [B*S][4096] bf16 (Q cols 0..2047, K cols 2048..4095), RoPE pre-applied
// Vt buffer: [B*H][128][2048] bf16 (V transposed: hd-major, s contiguous)
// Masking sentinels: finite so (masked) - (init) never yields exp2(0)=1.
#define MASKV (-30000.0f)
#define MINIT (-15000.0f)

__device__ __forceinline__ unsigned short f2bf(float f) {
  __hip_bfloat16 b = __float2bfloat16(f);
  return *reinterpret_cast<unsigned short*>(&b);
}
__device__ __forceinline__ void gl_lds16(const void* g, void* l) {
  __builtin_amdgcn_global_load_lds((const __attribute__((address_space(1))) unsigned int*)g,
                                   (__attribute__((address_space(3))) unsigned int*)l, 16, 0, 0);
}

// ---------------- fused fp32 -> bf16 conversion (single launch, 5 segments) ----
__global__ __launch_bounds__(256) void convert_all(const float* __restrict__ h,
                                                   const float* __restrict__ Wq,
                                                   const float* __restrict__ Wk,
                                                   const float* __restrict__ Wv,
                                                   const float* __restrict__ Wo,
                                                   __hip_bfloat16* __restrict__ hb,
                                                   __hip_bfloat16* __restrict__ wqkv,
                                                   __hip_bfloat16* __restrict__ wo_b) {
  int blk = blockIdx.x;
  const float* src;
  __hip_bfloat16* dst;
  int base;
  if (blk < 16384)      { src = h;  dst = hb;             base = 0; }
  else if (blk < 20480) { src = Wq; dst = wqkv;           base = 16384; }
  else if (blk < 24576) { src = Wk; dst = wqkv + 4194304; base = 20480; }
  else if (blk < 28672) { src = Wv; dst = wqkv + 8388608; base = 24576; }
  else                  { src = Wo; dst = wo_b;           base = 28672; }
  int i = (blk - base) * 256 + threadIdx.x;
  f32x4 v = ((const f32x4*)src)[i];
  u16x4 o;
  o[0] = f2bf(v[0]); o[1] = f2bf(v[1]); o[2] = f2bf(v[2]); o[3] = f2bf(v[3]);
  ((u16x4*)dst)[i] = o;
}

// ---------------- 256x256 8-wave B^T GEMM, single-barrier-per-tile ----------------
// R10 structure MINUS the intra-tile barriers. Cycle model (R15 post-mortem):
// per 64-K tile per CU, LDS reads ~2300 cyc and MFMA ~2460 cyc ran ADDITIVELY
// (4 barriers/tile held 8 waves in lockstep: read-burst then MFMA-burst).
// Only essential ordering is the END-of-tile vmcnt(0)+barrier:
//  - stage(T+1) writes into buf[nxt] are issued AFTER the end-of-(T-1) barrier,
//    and tile T-1's reads of buf[nxt] are register-complete before each wave's
//    barrier arrival (lgkm waits precede MFMA which precedes barrier) -> no WAR.
//  - vmcnt(0)+barrier at end of T makes stage(T+1) visible to all waves. 
// With one barrier/tile, waves desync and the compiler interleaves ds_read
// with MFMA in one basic block -> LDS and matrix pipes overlap.
// MODE 0: epilogue -> QK buffer with fused RoPE (n<4096) or Vt (transposed).
// MODE 1: epilogue -> float C row-major [M][N].
template <int MODE>
__global__ __launch_bounds__(512, 1) void gemm256(const __hip_bfloat16* __restrict__ A,
                                                  const __hip_bfloat16* __restrict__ Bw,
                                                  __hip_bfloat16* __restrict__ Cbf,
                                                  __hip_bfloat16* __restrict__ Vt,
                                                  float* __restrict__ Cf,
                                                  const float* __restrict__ fc,
                                                  const float* __restrict__ fs,
                                                  const int* __restrict__ posp,
                                                  int M, int N, int K) {
  __shared__ __hip_bfloat16 As[2][2][128 * 64];  // [buf][half][row*64+col]  64KB
  __shared__ __hip_bfloat16 Bs[2][2][128 * 64];  // 64KB
  const int tid = threadIdx.x;
  const int wid = tid >> 6, lane = tid & 63;
  const int l15 = lane & 15, l4 = lane >> 4;
  const int wm = wid >> 2, wn = wid & 3;  // 2 x 4 wave grid; wave owns 128x64

  const int nbn = N >> 8;
  const int nb = (M >> 8) * nbn;
  const int bid = blockIdx.x;
  const int swz = (bid & 7) * (nb >> 3) + (bid >> 3);  // XCD-contiguous (nb%8==0)
  const int bm = swz / nbn, bn = swz % nbn;

  const int NT = K >> 6;  // K-tiles of 64

#define STAGE_HALF(Q, BUF, K0G)                                                   \
  {                                                                               \
    if ((Q) < 2) {                                                                \
      const long rowb = (long)bm * 256 + (Q) * 128;                               \
      _Pragma("unroll") for (int i = 0; i < 2; i++) {                             \
        int c = i * 512 + tid, rr = c >> 3, jj = (c & 7) ^ (rr & 7);              \
        gl_lds16(A + (rowb + rr) * (long)K + (K0G) + jj * 8,                      \
                 &As[BUF][(Q)][0] + c * 8);                                       \
      }                                                                           \
    } else {                                                                      \
      const long rowb = (long)bn * 256 + ((Q) - 2) * 128;                         \
      _Pragma("unroll") for (int i = 0; i < 2; i++) {                             \
        int c = i * 512 + tid, rr = c >> 3, jj = (c & 7) ^ (rr & 7);              \
        gl_lds16(Bw + (rowb + rr) * (long)K + (K0G) + jj * 8,                     \
                 &Bs[BUF][(Q) - 2][0] + c * 8);                                   \
      }                                                                           \
    }                                                                             \
  }

  f32x4 acc[8][4] = {};

  // prologue: tiles 0 and 1 fully staged
#pragma unroll
  for (int q = 0; q < 4; ++q) STAGE_HALF(q, 0, 0);
#pragma unroll
  for (int q = 0; q < 4; ++q) STAGE_HALF(q, 1, 64);
  __syncthreads();  // vmcnt(0)+lgkm(0)+barrier

  for (int T = 0; T < NT; ++T) {
    const int cur = T & 1;
    const int nxt = cur ^ 1;
    const bool do_stage = (T >= 1) && (T + 1 < NT);
    const int k0n = (T + 1) << 6;

#pragma unroll
    for (int k2 = 0; k2 < 2; ++k2) {
      bf16x8 af[8], bg[4];
#pragma unroll
      for (int ni = 0; ni < 4; ni++) {
        int r = (wn & 1) * 64 + ni * 16 + l15;
        int j = (k2 * 4 + l4) ^ (r & 7);
        bg[ni] = *(const bf16x8*)(&Bs[cur][wn >> 1][0] + r * 64 + j * 8);
      }
#pragma unroll
      for (int mi = 0; mi < 8; mi++) {
        int r = mi * 16 + l15;
        int j = (k2 * 4 + l4) ^ (r & 7);
        af[mi] = *(const bf16x8*)(&As[cur][wm][0] + r * 64 + j * 8);
      }
      if (do_stage) {
        if (k2 == 0) { STAGE_HALF(0, nxt, k0n); STAGE_HALF(1, nxt, k0n); }
        else         { STAGE_HALF(2, nxt, k0n); STAGE_HALF(3, nxt, k0n); }
      }
      // no barrier: ds_read <-> MFMA free to interleave; waves desync
      __builtin_amdgcn_s_setprio(1);
#pragma unroll
      for (int mi = 0; mi < 8; mi++)
#pragma unroll
        for (int ni = 0; ni < 4; ni++)
          acc[mi][ni] = __builtin_amdgcn_mfma_f32_16x16x32_bf16(af[mi], bg[ni],
                                                                acc[mi][ni], 0, 0, 0);
      __builtin_amdgcn_s_setprio(0);
    }
    // single essential sync point per tile
    asm volatile("s_waitcnt vmcnt(0)" ::: "memory");
    __builtin_amdgcn_s_barrier();
    asm volatile("" ::: "memory");
  }
#undef STAGE_HALF

  // ---- epilogue ----
  if (MODE == 0) {
    if (bn * 256 < 4096) {
      const int pos = *posp;
#pragma unroll
      for (int mi = 0; mi < 8; mi++)
#pragma unroll
        for (int ni = 0; ni < 4; ni++) {
          int n = bn * 256 + wn * 64 + ni * 16 + l15;
          int hd = n & 127;
          int ip = hd >> 1;
          bool odd = hd & 1;
#pragma unroll
          for (int r = 0; r < 4; r++) {
            float v = acc[mi][ni][r];
            float p = __shfl_xor(v, 1, 64);
            int m = bm * 256 + wm * 128 + mi * 16 + l4 * 4 + r;
            int s = m & (SS - 1);
            float cv = fc[(long)(pos + s) * 64 + ip];
            float sv = fs[(long)(pos + s) * 64 + ip];
            float out = odd ? (p * sv + v * cv) : (v * cv - p * sv);
            Cbf[(long)m * 4096 + n] = __float2bfloat16(out);
          }
        }
    } else {
#pragma unroll
      for (int mi = 0; mi < 8; mi++)
#pragma unroll
        for (int ni = 0; ni < 4; ni++) {
          int e = bn * 256 + wn * 64 + ni * 16 + l15 - 4096;
          int hh = e >> 7, hd = e & 127;
          int m0 = bm * 256 + wm * 128 + mi * 16 + l4 * 4;
          int b = m0 >> 11, s0 = m0 & (SS - 1);
          u16x4 pk;
#pragma unroll
          for (int r = 0; r < 4; r++) pk[r] = f2bf(acc[mi][ni][r]);
          *(u16x4*)(Vt + (((long)(b * HH + hh) * 128 + hd) * SS + s0)) = pk;
        }
    }
  } else {
#pragma unroll
    for (int mi = 0; mi < 8; mi++)
#pragma unroll
      for (int ni = 0; ni < 4; ni++) {
        int n = bn * 256 + wn * 64 + ni * 16 + l15;
#pragma unroll
        for (int r = 0; r < 4; r++) {
          int m = bm * 256 + wm * 128 + mi * 16 + l4 * 4 + r;
          Cf[(long)m * N + n] = acc[mi][ni][r];
        }
      }
  }
}

// ---------------- causal flash attention (round-14, unchanged) ----------------
__global__ __launch_bounds__(256, 2) void attn_k(const __hip_bfloat16* __restrict__ qk,
                                                 const __hip_bfloat16* __restrict__ vt,
                                                 __hip_bfloat16* __restrict__ aout,
                                                 const int* __restrict__ posp) {
  __shared__ __hip_bfloat16 Ks[64 * 128];
  __shared__ __hip_bfloat16 Vs[128 * 64];
  __shared__ __hip_bfloat16 Ps[4][16 * 64];
  const int pos = *posp;
  const int orig = blockIdx.x;
  const int swz = (orig & 7) * 128 + (orig >> 3);
  const int qp = swz & 15, bh = swz >> 4;
  const int b = bh >> 4, h = bh & 15;
  const int tid = threadIdx.x;
  const int wave = tid >> 6, lane = tid & 63;
  const int l15 = lane & 15, l4 = lane >> 4;

  const long kbase = ((long)b * SS) * 4096 + 2048 + h * 128;
  const long vbase = ((long)bh * 128) * SS;
  const float sc2 = 0.08838834764831845f * 1.4426950408889634f;

  const int s_kr[4] = {(0 * 256 + tid) >> 4, (1 * 256 + tid) >> 4, (2 * 256 + tid) >> 4, (3 * 256 + tid) >> 4};
  const int s_kc = tid & 15;
  const int s_hd[4] = {(0 * 256 + tid) >> 3, (1 * 256 + tid) >> 3, (2 * 256 + tid) >> 3, (3 * 256 + tid) >> 3};
  const int s_vc = tid & 7;

  bf16x8 kreg[4], vreg[4];

#define LOADKV(T)                                                                             \
  {                                                                                           \
    const int kv0_ = (T) * 64;                                                                \
    _Pragma("unroll") for (int i = 0; i < 4; i++) {                                           \
      kreg[i] = *(const bf16x8*)(qk + kbase + (long)(kv0_ + s_kr[i]) * 4096 + s_kc * 8);      \
      vreg[i] = *(const bf16x8*)(vt + vbase + (long)s_hd[i] * SS + kv0_ + s_vc * 8);          \
    }                                                                                         \
  }

#define STAGE()                                                                               \
  {                                                                                           \
    _Pragma("unroll") for (int i = 0; i < 4; i++) {                                           \
      *(bf16x8*)(Ks + ((s_kr[i] * 128 + s_kc * 8) ^ ((s_kr[i] & 7) << 3))) = kreg[i];         \
      *(bf16x8*)(Vs + ((s_hd[i] * 64 + s_vc * 8) ^ ((s_hd[i] & 7) << 3))) = vreg[i];          \
    }                                                                                         \
  }

  for (int half = 0; half < 2; ++half) {
    const int qb = half ? (31 - qp) : qp;
    const int qwb = qb * 64 + wave * 16;

    bf16x8 qf[4];
#pragma unroll
    for (int kk = 0; kk < 4; kk++) {
      long row = (long)b * SS + qwb + l15;
      qf[kk] = *(const bf16x8*)(qk + row * 4096 + h * 128 + kk * 32 + l4 * 8);
    }

    f32x4 accO[8] = {};
    float mrun[4], lrun[4];
#pragma unroll
    for (int r = 0; r < 4; r++) { mrun[r] = MINIT; lrun[r] = 0.f; }

    int ntiles = (pos + qb * 64 + 63) / 64 + 1;
    if (ntiles > SS / 64) ntiles = SS / 64;
#define TT(t) (half ? (ntiles - 1 - (t)) : (t))

    LOADKV(TT(0));
    __syncthreads();
    STAGE();

    for (int t = 0; t < ntiles; ++t) {
      const int kv0 = TT(t) * 64;
      __syncthreads();
      if (t + 1 < ntiles) LOADKV(TT(t + 1));

      f32x4 sfr[4] = {};
      __builtin_amdgcn_s_setprio(1);
#pragma unroll
      for (int ni = 0; ni < 4; ni++) {
        const int key = ni * 16 + l15;
        const int sw = (key & 7) << 3;
#pragma unroll
        for (int kk = 0; kk < 4; kk++) {
          bf16x8 kf = *(const bf16x8*)(Ks + ((key * 128 + kk * 32 + l4 * 8) ^ sw));
          sfr[ni] = __builtin_amdgcn_mfma_f32_16x16x32_bf16(qf[kk], kf, sfr[ni], 0, 0, 0);
        }
      }
      __builtin_amdgcn_s_setprio(0);

      const bool needmask = (kv0 + 63) > (pos + qb * 64);
#pragma unroll
      for (int ni = 0; ni < 4; ni++)
#pragma unroll
        for (int r = 0; r < 4; r++) {
          float v = sfr[ni][r] * sc2;
          if (needmask) {
            int key = kv0 + ni * 16 + l15;
            int q = qwb + l4 * 4 + r;
            if (key > pos + q) v = MASKV;
          }
          sfr[ni][r] = v;
        }

      {
        f32x4 mx = sfr[0];
#pragma unroll
        for (int ni = 1; ni < 4; ni++)
#pragma unroll
          for (int r = 0; r < 4; r++) mx[r] = fmaxf(mx[r], sfr[ni][r]);
#pragma unroll
        for (int d = 1; d < 16; d <<= 1)
#pragma unroll
          for (int r = 0; r < 4; r++) mx[r] = fmaxf(mx[r], __shfl_xor(mx[r], d, 64));

        float growth = mx[0] - mrun[0];
#pragma unroll
        for (int r = 1; r < 4; r++) growth = fmaxf(growth, mx[r] - mrun[r]);
        if (!__all(growth <= 11.0f)) {
          float scal[4];
#pragma unroll
          for (int r = 0; r < 4; r++) {
            float mn = fmaxf(mrun[r], mx[r]);
            scal[r] = exp2f(mrun[r] - mn);
            mrun[r] = mn;
            lrun[r] *= scal[r];   // scal uniform across 16-lane group: valid on partials
          }
#pragma unroll
          for (int ni = 0; ni < 8; ni++)
#pragma unroll
            for (int r = 0; r < 4; r++) accO[ni][r] *= scal[r];
        }

        // per-lane partial sum; cross-lane reduce deferred to epilogue
#pragma unroll
        for (int ni = 0; ni < 4; ni++)
#pragma unroll
          for (int r = 0; r < 4; r++) {
            float p = exp2f(sfr[ni][r] - mrun[r]);
            lrun[r] += p;
            int prow = l4 * 4 + r;
            Ps[wave][(prow * 64 + ni * 16 + l15) ^ ((prow & 7) << 3)] = __float2bfloat16(p);
          }
      }

      __builtin_amdgcn_s_setprio(1);
#pragma unroll
      for (int kk = 0; kk < 2; kk++) {
        int prow = l15;
        bf16x8 pf = *(const bf16x8*)(Ps[wave] + ((prow * 64 + kk * 32 + l4 * 8) ^ ((prow & 7) << 3)));
#pragma unroll
        for (int ni = 0; ni < 8; ni++) {
          int hd = ni * 16 + l15;
          bf16x8 vf = *(const bf16x8*)(Vs + ((hd * 64 + kk * 32 + l4 * 8) ^ ((hd & 7) << 3)));
          accO[ni] = __builtin_amdgcn_mfma_f32_16x16x32_bf16(pf, vf, accO[ni], 0, 0, 0);
        }
      }
      __builtin_amdgcn_s_setprio(0);

      __syncthreads();
      if (t + 1 < ntiles) STAGE();
    }
#undef TT

    // deferred cross-lane lrun reduce (once per q-half)
#pragma unroll
    for (int d = 1; d < 16; d <<= 1)
#pragma unroll
      for (int r = 0; r < 4; r++) lrun[r] += __shfl_xor(lrun[r], d, 64);

    __hip_bfloat16* E = Ks + wave * 2048;
    {
      float inv[4];
#pragma unroll
      for (int r = 0; r < 4; r++) inv[r] = 1.0f / lrun[r];
#pragma unroll
      for (int ni = 0; ni < 8; ni++)
#pragma unroll
        for (int r = 0; r < 4; r++) {
          int row = l4 * 4 + r;
          E[(row * 128 + ni * 16 + l15) ^ ((row & 7) << 3)] =
              __float2bfloat16(accO[ni][r] * inv[r]);
        }
    }
    const long gb = ((long)b * SS + qwb) * 2048 + h * 128;
#pragma unroll
    for (int j = 0; j < 4; j++) {
      int row = j * 4 + l4;
      int c8 = l15 * 8;
      bf16x8 v = *(const bf16x8*)(E + ((row * 128 + c8) ^ ((row & 7) << 3)));
      *(bf16x8*)(aout + gb + (long)row * 2048 + c8) = v;
    }
  }
#undef LOADKV
#undef STAGE
}

extern "C" void kernel_launch(void* const* d_in, const int* in_sizes, int n_in,
                              void* d_out, int out_size, void* d_ws, size_t ws_size,
                              hipStream_t stream) {
  (void)in_sizes; (void)n_in; (void)out_size; (void)ws_size;
  const float* h  = (const float*)d_in[0];
  const float* Wq = (const float*)d_in[1];
  const float* Wk = (const float*)d_in[2];
  const float* Wv = (const float*)d_in[3];
  const float* Wo = (const float*)d_in[4];
  const float* fc = (const float*)d_in[7];
  const float* fs = (const float*)d_in[8];
  const int* pos  = (const int*)d_in[9];
  float* out = (float*)d_out;

  char* ws = (char*)d_ws;
  __hip_bfloat16* hb    = (__hip_bfloat16*)(ws);                 // 33,554,432 B
  __hip_bfloat16* wqkv  = (__hip_bfloat16*)(ws + 33554432);      // 25,165,824 B
  __hip_bfloat16* wo_b  = (__hip_bfloat16*)(ws + 58720256);      //  8,388,608 B
  __hip_bfloat16* qkbuf = (__hip_bfloat16*)(ws + 67108864);      // 67,108,864 B
  __hip_bfloat16* vt    = (__hip_bfloat16*)(ws + 134217728);     // 33,554,432 B
  __hip_bfloat16* aout  = hb;  // alias: hb dead after GEMM1

  // fused fp32 -> bf16 (h + Wq + Wk + Wv + Wo), single launch
  convert_all<<<32768, 256, 0, stream>>>(h, Wq, Wk, Wv, Wo, hb, wqkv, wo_b);

  // QKV projection + fused RoPE: M=8192, N=6144, K=2048  (32x24=768 blocks)
  gemm256<0><<<768, 512, 0, stream>>>(hb, wqkv, qkbuf, vt, nullptr, fc, fs, pos,
                                      8192, 6144, 2048);

  // causal flash attention (balanced, two-stream L2-local, 1024 blocks x 256 threads)
  attn_k<<<1024, 256, 0, stream>>>(qkbuf, vt, aout, pos);

  // output projection: M=8192, N=2048, K=2048 -> fp32 d_out  (32x8=256 blocks)
  gemm256<1><<<256, 512, 0, stream>>>(aout, wo_b, nullptr, nullptr, out, nullptr,
                                      nullptr, nullptr, 8192, 2048, 2048);
}